// Round 3
// baseline (138.368 us; speedup 1.0000x reference)
//
#include <hip/hip_runtime.h>
#include <hip/hip_bf16.h>

static constexpr int H = 512;
static constexpr int W = 512;
static constexpr int NIMG = 8;
static constexpr float BIGF = 1.0e6f;

static constexpr int SEG  = 32;        // rows per segment (one bitmask word)
static constexpr int NSEG = H / SEG;   // 16 segments per column
static constexpr int CPB  = 32;        // columns per block

// ws layout (floats):
//   F[16][H][W]  : 16 MiB  (t<8: EDT^2 of a_t, t>=8: EDT^2 of b_{t-8})
//   maxsq[16]    : task = dir*8+img
//   anyflag[16]

__global__ void k_init(float* __restrict__ maxsq, int* __restrict__ anyflag) {
    int t = threadIdx.x;
    if (t < 16) { maxsq[t] = 0.0f; anyflag[t] = 0; }
}

__global__ __launch_bounds__(CPB * NSEG)
void k_col_edt(const float* __restrict__ A, const float* __restrict__ B,
               float* __restrict__ F, int* __restrict__ anyflag) {
    const int col_l = threadIdx.x & (CPB - 1);
    const int seg   = threadIdx.x >> 5;          // 0..NSEG-1
    const int cg    = blockIdx.x;                // column group 0..W/CPB-1
    const int m16   = blockIdx.y;                // mask 0..15
    const int col   = cg * CPB + col_l;
    const float* src = (m16 < NIMG) ? (A + (size_t)m16 * H * W)
                                    : (B + (size_t)(m16 - NIMG) * H * W);
    float* f = F + (size_t)m16 * H * W;

    const int row0 = seg * SEG;

    // 1) load 32 rows of this column (independent, coalesced) -> bitmask
    unsigned int m = 0u;
    #pragma unroll
    for (int r = 0; r < SEG; ++r) {
        float px = src[(size_t)(row0 + r) * W + col];
        m |= (px > 0.5f ? 1u : 0u) << r;
    }

    // 2) per-segment summaries (global row index of highest/lowest set bit)
    const int NEG = -(1 << 21);   // sentinel: guarantees distance > 1e6 -> clamps
    const int POS =  (1 << 21);
    __shared__ int s_hi[NSEG][CPB];
    __shared__ int s_lo[NSEG][CPB];
    s_hi[seg][col_l] = m ? (row0 + (31 - __clz((int)m))) : NEG;
    s_lo[seg][col_l] = m ? (row0 + (__ffs((int)m) - 1)) : POS;

    if (__any(m != 0u)) {
        if ((threadIdx.x & 63) == 0) atomicOr(&anyflag[m16], 1);
    }
    __syncthreads();

    // 3) cross-segment carries
    int carry_dn = NEG;
    for (int t = 0; t < seg; ++t) carry_dn = max(carry_dn, s_hi[t][col_l]);
    int carry_up = POS;
    for (int t = seg + 1; t < NSEG; ++t) carry_up = min(carry_up, s_lo[t][col_l]);

    // 4) per-row exact axis-0 distance via bit scans, then clamp+square
    #pragma unroll
    for (int r = 0; r < SEG; ++r) {
        const int ig = row0 + r;
        unsigned int below = m & (0xFFFFFFFFu >> (31 - r));   // bits 0..r
        int pos_dn = below ? (row0 + (31 - __clz((int)below))) : carry_dn;
        unsigned int above = m & (0xFFFFFFFFu << r);          // bits r..31
        int pos_up = above ? (row0 + (__ffs((int)above) - 1)) : carry_up;
        int d = min(ig - pos_dn, pos_up - ig);
        float d1 = fminf((float)d, BIGF);
        f[(size_t)ig * W + col] = d1 * d1;
    }
}

__global__ void k_row_env(const float* __restrict__ A, const float* __restrict__ B,
                          const float* __restrict__ F, float* __restrict__ maxsq) {
    const int row  = blockIdx.x;      // 0..H-1
    const int task = blockIdx.y;      // 0..15
    const int img  = task & 7;
    const int dir  = task >> 3;       // 0: D_b at a-pixels ; 1: D_a at b-pixels
    const int fsel = (dir == 0) ? (NIMG + img) : img;
    const float* frow = F + (size_t)fsel * H * W + (size_t)row * W;
    const float* mrow = ((dir == 0) ? A : B) + (size_t)img * H * W + (size_t)row * W;

    __shared__ float sf[W];
    __shared__ float wmax[8];
    const int j = threadIdx.x;        // 0..W-1, block = 512
    sf[j] = frow[j];
    const bool mk = mrow[j] > 0.5f;
    __syncthreads();

    // exact lower envelope via expanding search with provable cutoff r^2 >= best
    float best = sf[j];
    for (int r = 1; r < W; ++r) {
        float rr = (float)(r * r);
        if (__all(rr >= best)) break;   // wave-uniform exact early exit
        int kl = j - r, kr = j + r;
        if (kl >= 0) best = fminf(best, rr + sf[kl]);
        if (kr < W)  best = fminf(best, rr + sf[kr]);
    }

    float v = mk ? best : 0.0f;
    #pragma unroll
    for (int off = 32; off > 0; off >>= 1)
        v = fmaxf(v, __shfl_down(v, off, 64));
    if ((j & 63) == 0) wmax[j >> 6] = v;
    __syncthreads();
    if (j == 0) {
        float mx = wmax[0];
        #pragma unroll
        for (int w = 1; w < 8; ++w) mx = fmaxf(mx, wmax[w]);
        atomicMax((int*)&maxsq[task], __float_as_int(mx));  // values >= 0
    }
}

__global__ void k_finalize(const float* __restrict__ maxsq, const int* __restrict__ anyflag,
                           float* __restrict__ out) {
    if (threadIdx.x == 0 && blockIdx.x == 0) {
        float s = 0.0f;
        for (int img = 0; img < NIMG; ++img) {
            bool empty = (anyflag[img] == 0) || (anyflag[NIMG + img] == 0);
            float loss;
            if (empty) {
                loss = 1.0f;
            } else {
                float hd = sqrtf(fmaxf(maxsq[img], maxsq[NIMG + img]));
                loss = 1.0f - 1.0f / (1.0f + hd);
            }
            s += loss;
        }
        out[0] = s * (1.0f / (float)NIMG);
    }
}

extern "C" void kernel_launch(void* const* d_in, const int* in_sizes, int n_in,
                              void* d_out, int out_size, void* d_ws, size_t ws_size,
                              hipStream_t stream) {
    const float* A = (const float*)d_in[0];
    const float* B = (const float*)d_in[1];
    float* F       = (float*)d_ws;
    float* maxsq   = F + (size_t)16 * H * W;
    int*   anyflag = (int*)(maxsq + 16);
    float* out     = (float*)d_out;

    hipLaunchKernelGGL(k_init, dim3(1), dim3(32), 0, stream, maxsq, anyflag);
    hipLaunchKernelGGL(k_col_edt, dim3(W / CPB, 16), dim3(CPB * NSEG), 0, stream,
                       A, B, F, anyflag);
    hipLaunchKernelGGL(k_row_env, dim3(H, 16), dim3(W), 0, stream, A, B, F, maxsq);
    hipLaunchKernelGGL(k_finalize, dim3(1), dim3(1), 0, stream, maxsq, anyflag, out);
}

// Round 4
// 33.948 us; speedup vs baseline: 4.0758x; 4.0758x over previous
//
#include <hip/hip_runtime.h>
#include <hip/hip_bf16.h>

static constexpr int H = 512;
static constexpr int W = 512;
static constexpr int NIMG = 8;

// ws layout:
//   F[16][H][W]  uint16 : 8 MiB  (t<8: axis-0 distance of a_t, t>=8: of b_{t-8};
//                                 0xFFFF = empty-column sentinel -> f = 1e12f)
//   maxsq[16]    float  : task = dir*8+img ; dir0 = max_{a} D_b^2, dir1 = max_{b} D_a^2
//   anyflag[16]  int    : t<8: any(a_t), t>=8: any(b_{t-8})

__device__ __forceinline__ int edt_d(unsigned int m, int r, int row0, int ig,
                                     int carry_dn, int carry_up) {
    unsigned int below = m & (0xFFFFFFFFu >> (31 - r));   // bits 0..r
    int pos_dn = below ? (row0 + (31 - __clz((int)below))) : carry_dn;
    unsigned int above = m & (0xFFFFFFFFu << r);          // bits r..31
    int pos_up = above ? (row0 + (__ffs((int)above) - 1)) : carry_up;
    return min(ig - pos_dn, pos_up - ig);
}

__global__ __launch_bounds__(128)
void k_col_edt(const float* __restrict__ A, const float* __restrict__ B,
               unsigned short* __restrict__ F, float* __restrict__ maxsq,
               int* __restrict__ anyflag) {
    const int tid  = threadIdx.x;
    const int quad = tid & 7;          // 4-column group within 32-col tile
    const int seg  = tid >> 3;         // 0..15 (32-row segment)
    const int cg   = blockIdx.x;       // 0..15
    const int m16  = blockIdx.y;       // 0..15

    // fold k_init: only this block touches the slots during this kernel
    if (cg == 0 && m16 == 0 && tid < 16) { maxsq[tid] = 0.0f; anyflag[tid] = 0; }

    const int colbase = cg * 32 + quad * 4;
    const float* src = (m16 < NIMG) ? (A + (size_t)m16 * H * W)
                                    : (B + (size_t)(m16 - NIMG) * H * W);
    unsigned short* f = F + (size_t)m16 * H * W;
    const int row0 = seg * 32;

    // 32 independent float4 loads -> 4 column bitmasks
    unsigned int m0 = 0, m1 = 0, m2 = 0, m3 = 0;
    #pragma unroll
    for (int r = 0; r < 32; ++r) {
        float4 v = *reinterpret_cast<const float4*>(src + (size_t)(row0 + r) * W + colbase);
        m0 |= (v.x > 0.5f ? 1u : 0u) << r;
        m1 |= (v.y > 0.5f ? 1u : 0u) << r;
        m2 |= (v.z > 0.5f ? 1u : 0u) << r;
        m3 |= (v.w > 0.5f ? 1u : 0u) << r;
    }

    const int NEGS = -(1 << 21), POSS = (1 << 21);
    __shared__ int s_hi[16][32];
    __shared__ int s_lo[16][32];
    int4 hi, lo;
    hi.x = m0 ? (row0 + 31 - __clz((int)m0)) : NEGS;
    hi.y = m1 ? (row0 + 31 - __clz((int)m1)) : NEGS;
    hi.z = m2 ? (row0 + 31 - __clz((int)m2)) : NEGS;
    hi.w = m3 ? (row0 + 31 - __clz((int)m3)) : NEGS;
    lo.x = m0 ? (row0 + __ffs((int)m0) - 1) : POSS;
    lo.y = m1 ? (row0 + __ffs((int)m1) - 1) : POSS;
    lo.z = m2 ? (row0 + __ffs((int)m2) - 1) : POSS;
    lo.w = m3 ? (row0 + __ffs((int)m3) - 1) : POSS;
    *reinterpret_cast<int4*>(&s_hi[seg][quad * 4]) = hi;
    *reinterpret_cast<int4*>(&s_lo[seg][quad * 4]) = lo;
    __syncthreads();

    // cross-segment carries (vectorized over the 4 owned columns)
    int4 cdn = {NEGS, NEGS, NEGS, NEGS};
    for (int t = 0; t < seg; ++t) {
        int4 h = *reinterpret_cast<int4*>(&s_hi[t][quad * 4]);
        cdn.x = max(cdn.x, h.x); cdn.y = max(cdn.y, h.y);
        cdn.z = max(cdn.z, h.z); cdn.w = max(cdn.w, h.w);
    }
    int4 cup = {POSS, POSS, POSS, POSS};
    for (int t = seg + 1; t < 16; ++t) {
        int4 l = *reinterpret_cast<int4*>(&s_lo[t][quad * 4]);
        cup.x = min(cup.x, l.x); cup.y = min(cup.y, l.y);
        cup.z = min(cup.z, l.z); cup.w = min(cup.w, l.w);
    }

    // per-row exact axis-0 distance, packed ushort4 stores
    #pragma unroll
    for (int r = 0; r < 32; ++r) {
        const int ig = row0 + r;
        ushort4 o;
        o.x = (unsigned short)min(edt_d(m0, r, row0, ig, cdn.x, cup.x), 65535);
        o.y = (unsigned short)min(edt_d(m1, r, row0, ig, cdn.y, cup.y), 65535);
        o.z = (unsigned short)min(edt_d(m2, r, row0, ig, cdn.z, cup.z), 65535);
        o.w = (unsigned short)min(edt_d(m3, r, row0, ig, cdn.w, cup.w), 65535);
        *reinterpret_cast<ushort4*>(f + (size_t)ig * W + colbase) = o;
    }
}

__global__ __launch_bounds__(512)
void k_row_env(const float* __restrict__ A, const float* __restrict__ B,
               const unsigned short* __restrict__ F, float* __restrict__ maxsq,
               int* __restrict__ anyflag) {
    const int task = blockIdx.y;            // 0..15
    const int img  = task & 7;
    const int dir  = task >> 3;             // 0: D_b at a-pixels ; 1: D_a at b-pixels
    const int wave = threadIdx.x >> 6;      // 0..7 -> row within block
    const int lane = threadIdx.x & 63;
    const int row  = blockIdx.x * 8 + wave;
    const int fsel = (dir == 0) ? (NIMG + img) : img;
    const unsigned short* frow = F + (size_t)fsel * H * W + (size_t)row * W;
    const float* mrow = ((dir == 0) ? A : B) + (size_t)img * H * W + (size_t)row * W;
    const int p0 = lane * 8;

    __shared__ float sf[8][528];            // [wave][8 pad | 512 | 8 pad]
    __shared__ float s_wmax[8];
    __shared__ int   s_wany[8];

    // independent 16B loads: f (8x u16) and mask (8x f32)
    uint4  fu  = *reinterpret_cast<const uint4*>(frow + p0);
    float4 mv0 = *reinterpret_cast<const float4*>(mrow + p0);
    float4 mv1 = *reinterpret_cast<const float4*>(mrow + p0 + 4);

    float w[24];
    {
        unsigned int uu[4] = {fu.x, fu.y, fu.z, fu.w};
        #pragma unroll
        for (int e = 0; e < 4; ++e) {
            int dl = (int)(uu[e] & 0xFFFFu);
            int dh = (int)(uu[e] >> 16);
            w[8 + 2 * e]     = (dl == 65535) ? 1.0e12f : (float)(dl * dl);
            w[8 + 2 * e + 1] = (dh == 65535) ? 1.0e12f : (float)(dh * dh);
        }
    }

    float* srow = &sf[wave][0];
    *reinterpret_cast<float4*>(srow + 8 + p0)     = make_float4(w[8],  w[9],  w[10], w[11]);
    *reinterpret_cast<float4*>(srow + 8 + p0 + 4) = make_float4(w[12], w[13], w[14], w[15]);
    if (lane == 0) {
        float4 pad = make_float4(1e12f, 1e12f, 1e12f, 1e12f);
        *reinterpret_cast<float4*>(srow)     = pad;
        *reinterpret_cast<float4*>(srow + 4) = pad;
    }
    if (lane == 63) {
        float4 pad = make_float4(1e12f, 1e12f, 1e12f, 1e12f);
        *reinterpret_cast<float4*>(srow + 520) = pad;
        *reinterpret_cast<float4*>(srow + 524) = pad;
    }
    // row buffer is private to this wave: lockstep ds_write -> ds_read, no barrier

    float4 l0 = *reinterpret_cast<float4*>(srow + p0);        // [p0-8 .. p0-5] + 8 pad
    float4 l1 = *reinterpret_cast<float4*>(srow + p0 + 4);
    float4 r0 = *reinterpret_cast<float4*>(srow + p0 + 16);
    float4 r1 = *reinterpret_cast<float4*>(srow + p0 + 20);
    w[0]  = l0.x; w[1]  = l0.y; w[2]  = l0.z; w[3]  = l0.w;
    w[4]  = l1.x; w[5]  = l1.y; w[6]  = l1.z; w[7]  = l1.w;
    w[16] = r0.x; w[17] = r0.y; w[18] = r0.z; w[19] = r0.w;
    w[20] = r1.x; w[21] = r1.y; w[22] = r1.z; w[23] = r1.w;

    bool mk[8];
    mk[0] = mv0.x > 0.5f; mk[1] = mv0.y > 0.5f; mk[2] = mv0.z > 0.5f; mk[3] = mv0.w > 0.5f;
    mk[4] = mv1.x > 0.5f; mk[5] = mv1.y > 0.5f; mk[6] = mv1.z > 0.5f; mk[7] = mv1.w > 0.5f;
    int anyb = 0;
    #pragma unroll
    for (int p = 0; p < 8; ++p) anyb |= (int)mk[p];

    // exact envelope, r<=8 fully in registers
    float best[8];
    #pragma unroll
    for (int p = 0; p < 8; ++p) best[p] = w[8 + p];
    #pragma unroll
    for (int r = 1; r <= 8; ++r) {
        const float rr = (float)(r * r);
        #pragma unroll
        for (int p = 0; p < 8; ++p)
            best[p] = fminf(best[p], fminf(rr + w[8 + p - r], rr + w[8 + p + r]));
    }

    // remaining candidates cost >= 81; rare exact fallback via LDS
    float bmax = 0.0f;
    #pragma unroll
    for (int p = 0; p < 8; ++p) bmax = fmaxf(bmax, mk[p] ? best[p] : 0.0f);
    if (!__all(bmax <= 81.0f)) {
        for (int r = 9; r < W; ++r) {
            const float rr = (float)(r * r);
            if (__all(rr >= bmax)) break;
            #pragma unroll
            for (int p = 0; p < 8; ++p) {
                int kl = p0 + p - r, kr = p0 + p + r;
                float cl = (kl >= 0) ? srow[8 + kl] : 1.0e12f;
                float cr = (kr < W)  ? srow[8 + kr] : 1.0e12f;
                best[p] = fminf(best[p], fminf(rr + cl, rr + cr));
            }
            bmax = 0.0f;
            #pragma unroll
            for (int p = 0; p < 8; ++p) bmax = fmaxf(bmax, mk[p] ? best[p] : 0.0f);
        }
    }

    // masked max: lane -> wave -> block -> atomic
    float v = 0.0f;
    #pragma unroll
    for (int p = 0; p < 8; ++p) v = fmaxf(v, mk[p] ? best[p] : 0.0f);
    #pragma unroll
    for (int off = 32; off > 0; off >>= 1)
        v = fmaxf(v, __shfl_down(v, off, 64));
    int wany = __any(anyb) ? 1 : 0;
    if (lane == 0) { s_wmax[wave] = v; s_wany[wave] = wany; }
    __syncthreads();
    if (threadIdx.x == 0) {
        float mx = s_wmax[0]; int af = s_wany[0];
        #pragma unroll
        for (int q = 1; q < 8; ++q) { mx = fmaxf(mx, s_wmax[q]); af |= s_wany[q]; }
        atomicMax((int*)&maxsq[task], __float_as_int(mx));   // values >= 0
        if (af) atomicOr(&anyflag[(dir == 0) ? img : (NIMG + img)], 1);
    }
}

__global__ void k_finalize(const float* __restrict__ maxsq, const int* __restrict__ anyflag,
                           float* __restrict__ out) {
    if (threadIdx.x == 0 && blockIdx.x == 0) {
        float s = 0.0f;
        for (int img = 0; img < NIMG; ++img) {
            bool empty = (anyflag[img] == 0) || (anyflag[NIMG + img] == 0);
            float loss;
            if (empty) {
                loss = 1.0f;
            } else {
                float hd = sqrtf(fmaxf(maxsq[img], maxsq[NIMG + img]));
                loss = 1.0f - 1.0f / (1.0f + hd);
            }
            s += loss;
        }
        out[0] = s * (1.0f / (float)NIMG);
    }
}

extern "C" void kernel_launch(void* const* d_in, const int* in_sizes, int n_in,
                              void* d_out, int out_size, void* d_ws, size_t ws_size,
                              hipStream_t stream) {
    const float* A = (const float*)d_in[0];
    const float* B = (const float*)d_in[1];
    unsigned short* F = (unsigned short*)d_ws;
    float* maxsq   = (float*)((char*)d_ws + (size_t)16 * H * W * sizeof(unsigned short));
    int*   anyflag = (int*)(maxsq + 16);
    float* out     = (float*)d_out;

    hipLaunchKernelGGL(k_col_edt, dim3(W / 32, 16), dim3(128), 0, stream,
                       A, B, F, maxsq, anyflag);
    hipLaunchKernelGGL(k_row_env, dim3(H / 8, 16), dim3(512), 0, stream,
                       A, B, F, maxsq, anyflag);
    hipLaunchKernelGGL(k_finalize, dim3(1), dim3(1), 0, stream, maxsq, anyflag, out);
}